// Round 13
// baseline (148.533 us; speedup 1.0000x reference)
//
#include <hip/hip_runtime.h>
#include <hip/hip_bf16.h>

using bf16 = __hip_bfloat16;

#define K 25
#define D0 7200
#define D1 3600
#define D2 1800

// pk stream word bases: [L0ch0][L0ch1][L1ch0][L1ch1][L2ch0][L2ch1], layout [k][d]
// pk word = ((idx*4) << 16) | bf16bits(w)   (high half = BYTE offset into table;
// idx*4 <= 57596 < 65536 fits 16 bits exactly)
#define PKB_L1 360000
#define PKB_L2 540000
// pbias layout: [L0ch0][L0ch1][L1ch0][L1ch1][L2ch0][L2ch1] (25200 entries)
#define NPB    25200

#define NT 1024  // threads per fused block (16 waves/CU; LDS caps blocks/CU at 1)

__device__ __forceinline__ float b2f(ushort u) {
  unsigned int w = ((unsigned int)u) << 16;
  float f; __builtin_memcpy(&f, &w, 4); return f;
}
__device__ __forceinline__ ushort f2b(float f) {
  bf16 h = __float2bfloat16(f);
  ushort u; __builtin_memcpy(&u, &h, 2); return u;
}
__device__ __forceinline__ float bits2f(unsigned int w) {
  float f; __builtin_memcpy(&f, &w, 4); return f;
}

// ---------------------------------------------------------------------------
// Prepack, one thread per output dim (25200 dims): reads 25 contiguous
// idx/w entries, writes pk[k*dout+d] lane-coalesced. Also fp32 biases,
// y zeroing, flags. Dtype votes (validated r2-r11) per block.
// fdt=1 -> floats are bf16; idt=1 -> knn is int64.
// ---------------------------------------------------------------------------
__global__ __launch_bounds__(256) void prepack_kernel(
    const void* __restrict__ x,
    const void* __restrict__ knn0, const void* __restrict__ knn1,
    const void* __restrict__ knn2,
    const void* __restrict__ wp0, const void* __restrict__ bp0,
    const void* __restrict__ wp1, const void* __restrict__ bp1,
    const void* __restrict__ wp2, const void* __restrict__ bp2,
    const void* __restrict__ wn0, const void* __restrict__ bn0,
    const void* __restrict__ wn1, const void* __restrict__ bn1,
    const void* __restrict__ wn2, const void* __restrict__ bn2,
    unsigned int* __restrict__ pk, float* __restrict__ pbias,
    float* __restrict__ y, int* __restrict__ flags) {
  __shared__ int s_flags[2];
  const int t = threadIdx.x;
  if (t < 64) {
    const unsigned int u = ((const unsigned int*)x)[t * 997];
    const unsigned int e = (u >> 23) & 0xFF;
    const unsigned long long m = __ballot((e >= 192) || (e <= 30));
    if (t == 0) s_flags[0] = (__popcll(m) >= 32) ? 1 : 0;
  } else if (t < 128) {
    const int l = t - 64;
    const unsigned int hi = ((const unsigned int*)knn0)[2 * l + 1];
    const unsigned long long m = __ballot(hi != 0);
    if (l == 0) s_flags[1] = (m == 0ULL) ? 1 : 0;
  }
  __syncthreads();
  const int fdt = s_flags[0], idt = s_flags[1];

  if (blockIdx.x == 0 && t == 0) {
    flags[0] = fdt; flags[1] = idt; flags[16] = 0;
  }

  const int gid = blockIdx.x * 256 + t;
  if (gid < NPB) {
    // map gid -> (layer, ch, d)
    int i = gid, d, dout, pkb;
    const void *kn, *wsel, *bsel;
    if (i < 14400) {
      const int ch = i / D0; d = i - ch * D0; dout = D0;
      pkb = ch * 180000; kn = knn0;
      wsel = ch ? wn0 : wp0; bsel = ch ? bn0 : bp0;
    } else if (i < 21600) {
      i -= 14400; const int ch = i / D1; d = i - ch * D1; dout = D1;
      pkb = PKB_L1 + ch * 90000; kn = knn1;
      wsel = ch ? wn1 : wp1; bsel = ch ? bn1 : bp1;
    } else {
      i -= 21600; const int ch = i / D2; d = i - ch * D2; dout = D2;
      pkb = PKB_L2 + ch * 45000; kn = knn2;
      wsel = ch ? wn2 : wp2; bsel = ch ? bn2 : bp2;
    }
    const int pos0 = d * K;
#pragma unroll
    for (int k = 0; k < K; ++k) {
      const unsigned int idx = idt ? ((const unsigned int*)kn)[2 * (pos0 + k)]
                                   : ((const unsigned int*)kn)[pos0 + k];
      const ushort wb = fdt ? ((const ushort*)wsel)[pos0 + k]
                            : f2b(((const float*)wsel)[pos0 + k]);
      // high half = byte offset into the uint-per-feature table: idx*4
      pk[pkb + k * dout + d] = ((idx * 4u) << 16) | (unsigned int)wb;
    }
    pbias[gid] = fdt ? b2f(((const ushort*)bsel)[d]) : ((const float*)bsel)[d];
  } else if (gid < NPB + 1024) {
    y[gid - NPB] = 0.0f;
  }
}

// ---------------------------------------------------------------------------
// One LCN layer inside LDS: out[d][0..1] = relu(sum_k w * in[idx][0..1] + b)
// Activation table: one uint per feature = (col1_bf16 << 16) | col0_bf16.
// pk high half = idx*4 = BYTE offset into the table.
// Minimal unpack: w = pw<<16; v0 = vv<<16; v1 = vv & 0xFFFF0000.
// r10 lesson: no dim-interleave (VGPR crunch de-pipelines); chain split e/o.
// ---------------------------------------------------------------------------
__device__ __forceinline__ void layer_run(char* ldsc, const unsigned int* __restrict__ pk,
                                          const float* __restrict__ pbias,
                                          int offInB, int offOutB, int pkb, int pbb,
                                          int dout) {
  const char* tab = ldsc + offInB;
  for (int d = threadIdx.x; d < dout; d += NT) {
    const unsigned int* s = pk + pkb + d;
    float a0e = 0.f, a0o = 0.f, a1e = 0.f, a1o = 0.f;
#pragma unroll
    for (int k = 0; k < K; ++k) {
      const unsigned int pw = s[k * dout];
      unsigned int vv;
      __builtin_memcpy(&vv, tab + (pw >> 16), 4);
      const float w  = bits2f(pw << 16);
      const float v0 = bits2f(vv << 16);
      const float v1 = bits2f(vv & 0xFFFF0000u);
      if (k & 1) {
        a0o = fmaf(w, v0, a0o);
        a1o = fmaf(w, v1, a1o);
      } else {
        a0e = fmaf(w, v0, a0e);
        a1e = fmaf(w, v1, a1e);
      }
    }
    const float bias = pbias[pbb + d];
    const float a0 = fmaxf(a0e + a0o + bias, 0.f);
    const float a1 = fmaxf(a1e + a1o + bias, 0.f);
    const unsigned int packed = ((unsigned int)f2b(a1) << 16) | (unsigned int)f2b(a0);
    __builtin_memcpy(ldsc + offOutB + d * 4, &packed, 4);
  }
}

// ---------------------------------------------------------------------------
// Fused network: block = (channel, batch-slice of 2), NT=1024 (16 waves/CU).
// LDS plan (bytes): L0: in@0 (57600) -> h0@57600 (28800);
// L1: h0@57600 -> h1@0 (14400); L2: h1@0 -> h2@14400 (7200); fc reads h2.
// Table uint per feature: low16 = col b0, high16 = col b0+1.
// ---------------------------------------------------------------------------
__global__ __launch_bounds__(NT) void lcn_fused(
    const void* __restrict__ x, const unsigned int* __restrict__ pk,
    const float* __restrict__ pbias,
    const void* __restrict__ fcpw, const void* __restrict__ fcnw,
    const void* __restrict__ fcpb, const void* __restrict__ fcnb,
    const void* __restrict__ f3w, const void* __restrict__ f3b,
    float* __restrict__ y, int* __restrict__ flags, void* __restrict__ out) {
  __shared__ ushort lds[43200];      // 86,400 B
  __shared__ float red[NT / 64][4];
  __shared__ int sflag;
  char* ldsc = (char*)lds;
  const int t = threadIdx.x;
  const int ch = blockIdx.x & 1;
  const int b0 = (blockIdx.x >> 1) * 2;

  if (t == 0) sflag = flags[0];
  __syncthreads();
  const int fdt = sflag;

  // ---- stage input rows b0, b0+1 (this channel's 14400 features) ----
  if (fdt) {
    const ushort* r0 = (const ushort*)x + (size_t)b0 * 28800 + ch * 14400;
    const ushort* r1 = r0 + 28800;
    for (int c = t; c < 3600; c += NT) {
      const ushort4 a = ((const ushort4*)r0)[c];
      const ushort4 b = ((const ushort4*)r1)[c];
      unsigned int* dst = (unsigned int*)&lds[c * 8];
      dst[0] = (unsigned int)a.x | ((unsigned int)b.x << 16);
      dst[1] = (unsigned int)a.y | ((unsigned int)b.y << 16);
      dst[2] = (unsigned int)a.z | ((unsigned int)b.z << 16);
      dst[3] = (unsigned int)a.w | ((unsigned int)b.w << 16);
    }
  } else {
    const float* r0 = (const float*)x + (size_t)b0 * 28800 + ch * 14400;
    const float* r1 = r0 + 28800;
    for (int c = t; c < 3600; c += NT) {
      const float4 a = ((const float4*)r0)[c];
      const float4 b = ((const float4*)r1)[c];
      unsigned int* dst = (unsigned int*)&lds[c * 8];
      dst[0] = (unsigned int)f2b(a.x) | ((unsigned int)f2b(b.x) << 16);
      dst[1] = (unsigned int)f2b(a.y) | ((unsigned int)f2b(b.y) << 16);
      dst[2] = (unsigned int)f2b(a.z) | ((unsigned int)f2b(b.z) << 16);
      dst[3] = (unsigned int)f2b(a.w) | ((unsigned int)f2b(b.w) << 16);
    }
  }
  __syncthreads();

  layer_run(ldsc, pk, pbias, 0, 57600, 0 + ch * 180000, 0 + ch * D0, D0);
  __syncthreads();
  layer_run(ldsc, pk, pbias, 57600, 0, PKB_L1 + ch * 90000, 14400 + ch * D1, D1);
  __syncthreads();
  layer_run(ldsc, pk, pbias, 0, 14400, PKB_L2 + ch * 45000, 21600 + ch * D2, D2);
  __syncthreads();

  // ---- fc: y[ch][o][b0..b0+1] = sum_d fw[o][d] * h2[d][.] ----
  {
    const void* fw = ch ? fcnw : fcpw;
    float a00 = 0.f, a01 = 0.f, a10 = 0.f, a11 = 0.f;
    for (int d = t; d < D2; d += NT) {
      unsigned int vv;
      __builtin_memcpy(&vv, ldsc + 14400 + d * 4, 4);
      const float v0 = bits2f(vv << 16);
      const float v1 = bits2f(vv & 0xFFFF0000u);
      const float w0 = fdt ? b2f(((const ushort*)fw)[d]) : ((const float*)fw)[d];
      const float w1 = fdt ? b2f(((const ushort*)fw)[D2 + d]) : ((const float*)fw)[D2 + d];
      a00 = fmaf(w0, v0, a00); a01 = fmaf(w0, v1, a01);
      a10 = fmaf(w1, v0, a10); a11 = fmaf(w1, v1, a11);
    }
#pragma unroll
    for (int off = 32; off > 0; off >>= 1) {
      a00 += __shfl_down(a00, off);
      a01 += __shfl_down(a01, off);
      a10 += __shfl_down(a10, off);
      a11 += __shfl_down(a11, off);
    }
    const int wave = t >> 6, lane = t & 63;
    if (lane == 0) {
      red[wave][0] = a00; red[wave][1] = a01; red[wave][2] = a10; red[wave][3] = a11;
    }
    __syncthreads();
    if (t == 0) {
      float s00 = 0.f, s01 = 0.f, s10 = 0.f, s11 = 0.f;
#pragma unroll
      for (int wv = 0; wv < NT / 64; ++wv) {
        s00 += red[wv][0]; s01 += red[wv][1]; s10 += red[wv][2]; s11 += red[wv][3];
      }
      atomicAdd(&y[(ch * 2 + 0) * 256 + b0], s00);
      atomicAdd(&y[(ch * 2 + 0) * 256 + b0 + 1], s01);
      atomicAdd(&y[(ch * 2 + 1) * 256 + b0], s10);
      atomicAdd(&y[(ch * 2 + 1) * 256 + b0 + 1], s11);
    }
  }

  // ---- last-done block computes the final combine (round-5-validated) ----
  __syncthreads();
  if (t == 0) {
    __threadfence();
    sflag = (atomicAdd(&flags[16], 1) == (int)gridDim.x - 1) ? 1 : 0;
  }
  __syncthreads();
  if (sflag && t < 256) {
    const int b = t;
    const float y0 = atomicAdd(&y[0 * 256 + b], 0.0f);
    const float y1 = atomicAdd(&y[1 * 256 + b], 0.0f);
    const float y2 = atomicAdd(&y[2 * 256 + b], 0.0f);
    const float y3 = atomicAdd(&y[3 * 256 + b], 0.0f);
    const float bp0v = fdt ? b2f(((const ushort*)fcpb)[0]) : ((const float*)fcpb)[0];
    const float bp1v = fdt ? b2f(((const ushort*)fcpb)[1]) : ((const float*)fcpb)[1];
    const float bn0v = fdt ? b2f(((const ushort*)fcnb)[0]) : ((const float*)fcnb)[0];
    const float bn1v = fdt ? b2f(((const ushort*)fcnb)[1]) : ((const float*)fcnb)[1];
    const float h0v = fmaxf(y0 + bp0v, 0.f);
    const float h1v = fmaxf(y1 + bp1v, 0.f);
    const float h2v = fmaxf(y2 + bn0v, 0.f);
    const float h3v = fmaxf(y3 + bn1v, 0.f);
#pragma unroll
    for (int o = 0; o < 2; ++o) {
      float w0, w1, w2, w3, bb;
      if (fdt) {
        const ushort* fp = (const ushort*)f3w;
        w0 = b2f(fp[o * 4 + 0]); w1 = b2f(fp[o * 4 + 1]);
        w2 = b2f(fp[o * 4 + 2]); w3 = b2f(fp[o * 4 + 3]);
        bb = b2f(((const ushort*)f3b)[o]);
      } else {
        const float* fp = (const float*)f3w;
        w0 = fp[o * 4 + 0]; w1 = fp[o * 4 + 1];
        w2 = fp[o * 4 + 2]; w3 = fp[o * 4 + 3];
        bb = ((const float*)f3b)[o];
      }
      float r = bb;
      r = fmaf(w0, h0v, r); r = fmaf(w1, h1v, r);
      r = fmaf(w2, h2v, r); r = fmaf(w3, h3v, r);
      if (fdt) ((ushort*)out)[b * 2 + o] = f2b(r);
      else     ((float*)out)[b * 2 + o] = r;
    }
  }
}

extern "C" void kernel_launch(void* const* d_in, const int* in_sizes, int n_in,
                              void* d_out, int out_size, void* d_ws, size_t ws_size,
                              hipStream_t stream) {
  const void* x    = d_in[0];
  const void* knn0 = d_in[1];
  const void* knn1 = d_in[2];
  const void* knn2 = d_in[3];
  const void* wp0  = d_in[4];  const void* bp0 = d_in[5];
  const void* wp1  = d_in[6];  const void* bp1 = d_in[7];
  const void* wp2  = d_in[8];  const void* bp2 = d_in[9];
  const void* fcpw = d_in[10]; const void* fcpb = d_in[11];
  const void* wn0  = d_in[12]; const void* bn0 = d_in[13];
  const void* wn1  = d_in[14]; const void* bn1 = d_in[15];
  const void* wn2  = d_in[16]; const void* bn2 = d_in[17];
  const void* fcnw = d_in[18]; const void* fcnb = d_in[19];
  const void* f3w  = d_in[20]; const void* f3b  = d_in[21];

  char* ws = (char*)d_ws;
  unsigned int* pk = (unsigned int*)(ws);         // 630000*4 = 2,520,000 B
  float* pbias = (float*)(ws + 2520000);          // 25200*4  =   100,800 B
  float* y     = (float*)(ws + 2620800);          // 1024*4   =     4,096 B
  int* flags   = (int*)(ws + 2624896);            // flags[0..1], flags[16]

  // tasks: 25200 dims + 1024 y-zero = 26224 -> 103 blocks of 256
  prepack_kernel<<<103, 256, 0, stream>>>(x, knn0, knn1, knn2,
                                          wp0, bp0, wp1, bp1, wp2, bp2,
                                          wn0, bn0, wn1, bn1, wn2, bn2,
                                          pk, pbias, y, flags);

  lcn_fused<<<256, NT, 0, stream>>>(x, pk, pbias, fcpw, fcnw, fcpb, fcnb,
                                    f3w, f3b, y, flags, d_out);
}